// Round 14
// baseline (257.316 us; speedup 1.0000x reference)
//
#include <hip/hip_runtime.h>
#include <hip/hip_bf16.h>
#include <stdint.h>
#include <math.h>

#define NHEADS 16
#define DK 64
#define BATCH 2
#define SEQ 2048
#define DMODEL 1024
#define MROWS (BATCH*SEQ)   // 4096

typedef __bf16 bf16x8 __attribute__((ext_vector_type(8)));
typedef float  f32x4  __attribute__((ext_vector_type(4)));
typedef float  f32x16 __attribute__((ext_vector_type(16)));

typedef const __attribute__((address_space(1))) void* gas_ptr;
typedef       __attribute__((address_space(3))) void* las_ptr;

__device__ __forceinline__ void async16(const void* g, void* l) {
  __builtin_amdgcn_global_load_lds((gas_ptr)g, (las_ptr)l, 16, 0, 0);
}

__device__ __forceinline__ unsigned short f2bf_raw(float f) {
  __hip_bfloat16 h = __float2bfloat16(f);
  return *reinterpret_cast<unsigned short*>(&h);
}

// raw v_exp_f32 (2^x), no ocml denormal guard
__device__ __forceinline__ float fast_exp2(float x) {
#if __has_builtin(__builtin_amdgcn_exp2f)
  return __builtin_amdgcn_exp2f(x);
#else
  float r;
  asm("v_exp_f32 %0, %1\ns_nop 1" : "=v"(r) : "v"(x));
  return r;
#endif
}

// v_cvt_pk_bf16_f32: dst = {bf16(lo) in [15:0], bf16(hi) in [31:16]}
__device__ __forceinline__ uint32_t pk_bf16(float lo, float hi2) {
  uint32_t r;
  asm("v_cvt_pk_bf16_f32 %0, %1, %2" : "=v"(r) : "v"(lo), "v"(hi2));
  return r;
}

// native permlane32_swap: a' = {a.lo32, b.lo32}, b' = {a.hi32, b.hi32}
__device__ __forceinline__ void half_swap(uint32_t& a, uint32_t& b) {
  auto r = __builtin_amdgcn_permlane32_swap(a, b, false, false);
  a = (uint32_t)r[0];
  b = (uint32_t)r[1];
}

// bit-select: msel all-ones -> s, zeros -> c  (maps to v_bfi_b32)
__device__ __forceinline__ float mask_sel(uint32_t msel, float s, float c) {
  uint32_t su = __float_as_uint(s), cu = __float_as_uint(c);
  return __uint_as_float((msel & su) | (~msel & cu));
}

__device__ __forceinline__ f32x16 zero16() {
  f32x16 z;
#pragma unroll
  for (int i = 0; i < 16; ++i) z[i] = 0.f;
  return z;
}

// ---------------- cast kernel ----------------
__global__ void cast_kernel(const float* __restrict__ q,
                            const float* __restrict__ k,
                            const float* __restrict__ v,
                            const float* __restrict__ w0,
                            const float* __restrict__ w1,
                            const float* __restrict__ w2,
                            const float* __restrict__ w3,
                            ushort4* __restrict__ out) {
  int i = blockIdx.x * 256 + threadIdx.x;
  const float* src;
  int local;
  if (i < 3145728) {
    int seg = i >> 20;
    src = (seg == 0) ? q : (seg == 1) ? k : v;
    local = i & 1048575;
  } else {
    int j = i - 3145728;
    int seg = j >> 18;
    src = (seg == 0) ? w0 : (seg == 1) ? w1 : (seg == 2) ? w2 : w3;
    local = j & 262143;
  }
  float4 f = reinterpret_cast<const float4*>(src)[local];
  ushort4 u;
  u.x = f2bf_raw(f.x); u.y = f2bf_raw(f.y);
  u.z = f2bf_raw(f.z); u.w = f2bf_raw(f.w);
  out[i] = u;
}

// ---------------- mask pack kernel (int4 + shfl nibble-OR tree) ----------------
__global__ void mask_kernel(const int* __restrict__ mask,
                            uint32_t* __restrict__ bits) {
  int bi = blockIdx.x;
  int lane = threadIdx.x & 63, wid = threadIdx.x >> 6;
  size_t base = (size_t)bi * 1024 + (size_t)wid * 256;  // int index
  int4 q4 = reinterpret_cast<const int4*>(mask + base)[lane];
  uint32_t nib = (q4.x != 0 ? 1u : 0u) | (q4.y != 0 ? 2u : 0u) |
                 (q4.z != 0 ? 4u : 0u) | (q4.w != 0 ? 8u : 0u);
  nib <<= (lane & 7) * 4;
  nib |= (uint32_t)__shfl_xor((int)nib, 1);
  nib |= (uint32_t)__shfl_xor((int)nib, 2);
  nib |= (uint32_t)__shfl_xor((int)nib, 4);
  if ((lane & 7) == 0) bits[(base >> 5) + (lane >> 3)] = nib;
}

// ---------------- GEMM core: BK=64, XOR-swizzled LDS ----------
// Per K-step/wave: 8 global_load_lds + 16 ds_read_b128 + 32 MFMA, 2 barriers.
// LDS[row][s] = global[row][s^(row&7)]; 16x16x32 fragment slot = kc*4 + lg.

__device__ __forceinline__ void gemm_core_128(
    const __hip_bfloat16* __restrict__ A, const __hip_bfloat16* __restrict__ Bw,
    int K, int m0, int n0,
    __hip_bfloat16* sA, __hip_bfloat16* sB, f32x4 acc[4][4]) {
  const int lane = threadIdx.x & 63;
  const int wid  = threadIdx.x >> 6;
  const int wr = wid >> 1, wc = wid & 1;
  const int l15 = lane & 15, lg = lane >> 4;
  const int sw = l15 & 7;
  const int crow8 = lane >> 3;
  const int cslot = lane & 7;

#pragma unroll
  for (int mi = 0; mi < 4; ++mi)
#pragma unroll
    for (int ni = 0; ni < 4; ++ni) acc[mi][ni] = f32x4{0.f, 0.f, 0.f, 0.f};

  for (int k0 = 0; k0 < K; k0 += 64) {
#pragma unroll
    for (int c0 = 0; c0 < 4; ++c0) {
      int c = wid + c0 * 4;
      int row = c * 8 + crow8;
      int scol = (cslot ^ (row & 7)) * 8;
      async16(A  + (size_t)(m0 + row) * K + k0 + scol,
              (char*)sA + c * 1024 + lane * 16);
      async16(Bw + (size_t)(n0 + row) * K + k0 + scol,
              (char*)sB + c * 1024 + lane * 16);
    }
    __syncthreads();
#pragma unroll
    for (int kc = 0; kc < 2; ++kc) {
      bf16x8 af[4], bfr[4];
#pragma unroll
      for (int mi = 0; mi < 4; ++mi)
        af[mi] = *reinterpret_cast<const bf16x8*>(
            &sA[(wr * 64 + mi * 16 + l15) * 64 + (((kc * 4 + lg) ^ sw) * 8)]);
#pragma unroll
      for (int ni = 0; ni < 4; ++ni)
        bfr[ni] = *reinterpret_cast<const bf16x8*>(
            &sB[(wc * 64 + ni * 16 + l15) * 64 + (((kc * 4 + lg) ^ sw) * 8)]);
      __builtin_amdgcn_s_setprio(1);
#pragma unroll
      for (int mi = 0; mi < 4; ++mi)
#pragma unroll
        for (int ni = 0; ni < 4; ++ni)
          acc[mi][ni] = __builtin_amdgcn_mfma_f32_16x16x32_bf16(
              af[mi], bfr[ni], acc[mi][ni], 0, 0, 0);
      __builtin_amdgcn_s_setprio(0);
    }
    __syncthreads();
  }
}

// QKV projection: z 0=Q (pre-scaled by 0.125*log2e), 1=K head-major, 2=V transposed
// LDS re-tile epilogue for coalesced 16B stores (verified R12).
__global__ __launch_bounds__(256, 3) void qkv_gemm_kernel(
    const __hip_bfloat16* __restrict__ Xq, const __hip_bfloat16* __restrict__ Xk,
    const __hip_bfloat16* __restrict__ Xv,
    const __hip_bfloat16* __restrict__ Wq, const __hip_bfloat16* __restrict__ Wk,
    const __hip_bfloat16* __restrict__ Wv,
    const float* __restrict__ bq, const float* __restrict__ bk,
    const float* __restrict__ bv,
    __hip_bfloat16* __restrict__ Qh, __hip_bfloat16* __restrict__ Kh,
    __hip_bfloat16* __restrict__ VhT) {
  __shared__ __attribute__((aligned(16))) char smem[128 * 136 * 2];  // 34816B
  __hip_bfloat16* sA = (__hip_bfloat16*)smem;
  __hip_bfloat16* sB = (__hip_bfloat16*)(smem + 16384);
  const int z = blockIdx.z;
  const __hip_bfloat16* A  = (z == 0) ? Xq : (z == 1) ? Xk : Xv;
  const __hip_bfloat16* Bw = (z == 0) ? Wq : (z == 1) ? Wk : Wv;
  const float* bias        = (z == 0) ? bq : (z == 1) ? bk : bv;
  __hip_bfloat16* Co       = (z == 0) ? Qh : (z == 1) ? Kh : VhT;
  const int m0 = blockIdx.x * 128, n0 = blockIdx.y * 128;
  f32x4 acc[4][4];
  gemm_core_128(A, Bw, DMODEL, m0, n0, sA, sB, acc);

  const int tid = threadIdx.x, lane = tid & 63, wid = tid >> 6;
  const int wr = wid >> 1, wc = wid & 1;
  const int l15 = lane & 15, lg = lane >> 4;
  const float osc = (z == 0) ? 0.18033688f : 1.0f;  // (1/8)*log2(e)
  const int PITCH = 136;
  __hip_bfloat16* sT = (__hip_bfloat16*)smem;

  if (z != 2) {
#pragma unroll
    for (int mi = 0; mi < 4; ++mi)
#pragma unroll
      for (int ni = 0; ni < 4; ++ni) {
        int jl = wc * 64 + ni * 16 + l15;
        float bj = bias[n0 + jl];
#pragma unroll
        for (int r = 0; r < 4; ++r) {
          int il = wr * 64 + mi * 16 + lg * 4 + r;
          sT[il * PITCH + jl] = __float2bfloat16((acc[mi][ni][r] + bj) * osc);
        }
      }
    __syncthreads();
#pragma unroll
    for (int u = 0; u < 8; ++u) {
      int t2 = tid + u * 256;
      int row = t2 >> 4, c8 = (t2 & 15) * 8;
      bf16x8 val = *reinterpret_cast<const bf16x8*>(&sT[row * PITCH + c8]);
      int ig = m0 + row, jg = n0 + c8;
      int bb = ig >> 11, s = ig & 2047, hh = jg >> 6, d = jg & 63;
      *reinterpret_cast<bf16x8*>(
          &Co[((size_t)(bb * NHEADS + hh) * SEQ + s) * DK + d]) = val;
    }
  } else {
#pragma unroll
    for (int mi = 0; mi < 4; ++mi)
#pragma unroll
      for (int ni = 0; ni < 4; ++ni) {
        int jl = wc * 64 + ni * 16 + l15;
        float bj = bias[n0 + jl];
        int il0 = wr * 64 + mi * 16 + lg * 4;
        ushort4 st4;
        st4.x = f2bf_raw(acc[mi][ni][0] + bj);
        st4.y = f2bf_raw(acc[mi][ni][1] + bj);
        st4.z = f2bf_raw(acc[mi][ni][2] + bj);
        st4.w = f2bf_raw(acc[mi][ni][3] + bj);
        *reinterpret_cast<ushort4*>(&sT[jl * PITCH + il0]) = st4;
      }
    __syncthreads();
#pragma unroll
    for (int u = 0; u < 8; ++u) {
      int t2 = tid + u * 256;
      int row = t2 >> 4, i8 = (t2 & 15) * 8;
      bf16x8 val = *reinterpret_cast<const bf16x8*>(&sT[row * PITCH + i8]);
      int jg = n0 + row, hh = jg >> 6, d = jg & 63;
      int ig0 = m0 + i8, bb = ig0 >> 11, s0 = ig0 & 2047;
      *reinterpret_cast<bf16x8*>(
          &Co[((size_t)(bb * NHEADS + hh) * DK + d) * SEQ + s0]) = val;
    }
  }
}

// Output projection: 64x128 tile (512 blocks = 2/CU), BK=64, same swizzle.
// Waves: wr = wid>>1 (row 32-band), wc = wid&1 (col 64-half); acc[2][4].
__global__ __launch_bounds__(256, 3) void out_gemm_kernel(
    const __hip_bfloat16* __restrict__ A, const __hip_bfloat16* __restrict__ Ww,
    const float* __restrict__ bias, float* __restrict__ C) {
  __shared__ __attribute__((aligned(16))) char smem[8192 + 16384];
  __hip_bfloat16* sA = (__hip_bfloat16*)smem;            // 64x64
  __hip_bfloat16* sB = (__hip_bfloat16*)(smem + 8192);   // 128x64
  const int m0 = blockIdx.x * 64, n0 = blockIdx.y * 128;
  const int lane = threadIdx.x & 63, wid = threadIdx.x >> 6;
  const int wr = wid >> 1, wc = wid & 1;
  const int l15 = lane & 15, lg = lane >> 4;
  const int sw = l15 & 7;
  const int crow8 = lane >> 3;
  const int cslot = lane & 7;

  f32x4 acc[2][4];
#pragma unroll
  for (int mi = 0; mi < 2; ++mi)
#pragma unroll
    for (int ni = 0; ni < 4; ++ni) acc[mi][ni] = f32x4{0.f, 0.f, 0.f, 0.f};

  for (int k0 = 0; k0 < DMODEL; k0 += 64) {
    // A: 8 chunks (64 rows), B: 16 chunks (128 rows)
#pragma unroll
    for (int c0 = 0; c0 < 2; ++c0) {
      int c = wid + c0 * 4;
      int row = c * 8 + crow8;
      int scol = (cslot ^ (row & 7)) * 8;
      async16(A + (size_t)(m0 + row) * DMODEL + k0 + scol,
              (char*)sA + c * 1024 + lane * 16);
    }
#pragma unroll
    for (int c0 = 0; c0 < 4; ++c0) {
      int c = wid + c0 * 4;
      int row = c * 8 + crow8;
      int scol = (cslot ^ (row & 7)) * 8;
      async16(Ww + (size_t)(n0 + row) * DMODEL + k0 + scol,
              (char*)sB + c * 1024 + lane * 16);
    }
    __syncthreads();
#pragma unroll
    for (int kc = 0; kc < 2; ++kc) {
      bf16x8 af[2], bfr[4];
#pragma unroll
      for (int mi = 0; mi < 2; ++mi)
        af[mi] = *reinterpret_cast<const bf16x8*>(
            &sA[(wr * 32 + mi * 16 + l15) * 64 + (((kc * 4 + lg) ^ sw) * 8)]);
#pragma unroll
      for (int ni = 0; ni < 4; ++ni)
        bfr[ni] = *reinterpret_cast<const bf16x8*>(
            &sB[(wc * 64 + ni * 16 + l15) * 64 + (((kc * 4 + lg) ^ sw) * 8)]);
      __builtin_amdgcn_s_setprio(1);
#pragma unroll
      for (int mi = 0; mi < 2; ++mi)
#pragma unroll
        for (int ni = 0; ni < 4; ++ni)
          acc[mi][ni] = __builtin_amdgcn_mfma_f32_16x16x32_bf16(
              af[mi], bfr[ni], acc[mi][ni], 0, 0, 0);
      __builtin_amdgcn_s_setprio(0);
    }
    __syncthreads();
  }

#pragma unroll
  for (int mi = 0; mi < 2; ++mi)
#pragma unroll
    for (int ni = 0; ni < 4; ++ni) {
      int j = n0 + wc * 64 + ni * 16 + l15;
      float bj = bias[j];
#pragma unroll
      for (int r = 0; r < 4; ++r) {
        int i = m0 + wr * 32 + mi * 16 + lg * 4 + r;
        C[(size_t)i * DMODEL + j] = acc[mi][ni][r] + bj;
      }
    }
}

// ---------------- flash attention: 8 waves = 2 KV-split groups x 4 q-waves ----
// (identical to R9/R11/R12 math — race-verified template; bh0 for split launch)

__global__ __launch_bounds__(512, 4) void attn_kernel(
    const __hip_bfloat16* __restrict__ Qh, const __hip_bfloat16* __restrict__ Kh,
    const __hip_bfloat16* __restrict__ VhT, const uint32_t* __restrict__ mbits,
    __hip_bfloat16* __restrict__ AO, int bh0) {
  __shared__ char pool[65536 + 512 + 512];
  __hip_bfloat16* Kpool = (__hip_bfloat16*)pool;
  __hip_bfloat16* Vpool = (__hip_bfloat16*)(pool + 32768);
  float* sRed = (float*)(pool + 65536);
  float* lC   = (float*)(pool + 65536 + 512);
  float* accC = (float*)pool;  // alias of K pool, used only after final barrier

  const int tid = threadIdx.x, lane = tid & 63, wid = tid >> 6;
  const int grp = wid >> 2, wq = wid & 3;
  const int ltid = tid & 255;
  const int l31 = lane & 31, hi = lane >> 5;
  const int sw = l31 & 7;
  const int bh = bh0 + blockIdx.y, b = bh >> 4, h = bh & 15;
  const int q0g = blockIdx.x * 128 + wq * 32;
  const int kvbase = grp * (SEQ / 2);

  const __hip_bfloat16* Qp = Qh  + (size_t)bh * SEQ * DK;
  const __hip_bfloat16* Kp = Kh  + (size_t)bh * SEQ * DK;
  const __hip_bfloat16* Vp = VhT + (size_t)bh * DK * SEQ;
  const uint32_t* mb = mbits + (size_t)b * SEQ * (SEQ / 32)
                             + (size_t)(q0g + l31) * (SEQ / 32) + (kvbase >> 5);
  float* sRedW = &sRed[wq * 32];

  bf16x8 qf[4];
#pragma unroll
  for (int dc = 0; dc < 4; ++dc)
    qf[dc] = *reinterpret_cast<const bf16x8*>(
        &Qp[(size_t)(q0g + l31) * DK + dc * 16 + hi * 8]);

  f32x16 acc0 = zero16(), acc1 = zero16();
  float l_run = 0.f;

#define STAGE(kv0_, s_)                                                        \
  {                                                                            \
    _Pragma("unroll")                                                          \
    for (int u = 0; u < 2; ++u) {                                              \
      int c = ltid + u * 256;                                                  \
      int row = c >> 3, ss = (c & 7) ^ (row & 7);                              \
      async16(Kp + (size_t)(kvbase + (kv0_) + row) * DK + ss * 8,              \
              (char*)(Kpool + (grp * 2 + (s_)) * 4096) + c * 16);              \
      async16(Vp + (size_t)row * SEQ + kvbase + (kv0_) + ss * 8,               \
              (char*)(Vpool + (grp * 2 + (s_)) * 4096) + c * 16);              \
    }                                                                          \
  }

  STAGE(0, 0);
  uint2 mw = *reinterpret_cast<const uint2*>(mb);
  asm volatile("s_waitcnt vmcnt(0)" ::: "memory");
  __syncthreads();

  const int NT = SEQ / 2 / 64;  // 16 tiles per group
  for (int t = 0; t < NT; ++t) {
    const int cur = t & 1;
    if (t + 1 < NT) STAGE((t + 1) * 64, cur ^ 1);

    uint2 mw_next;
    if (t + 1 < NT) mw_next = *reinterpret_cast<const uint2*>(mb + (t + 1) * 2);
    uint32_t w0 = mw.x >> (4 * hi), w1 = mw.y >> (4 * hi);

    const __hip_bfloat16* ks = Kpool + (grp * 2 + cur) * 4096;
    const __hip_bfloat16* vs = Vpool + (grp * 2 + cur) * 4096;

    // S^T = K . Q^T (scores in log2 units)
    f32x16 s0 = zero16(), s1 = zero16();
    __builtin_amdgcn_s_setprio(1);
#pragma unroll
    for (int dc = 0; dc < 4; ++dc) {
      bf16x8 k0 = *reinterpret_cast<const bf16x8*>(
          &ks[(size_t)(l31) * 64 + (((dc * 2 + hi) ^ sw) * 8)]);
      bf16x8 k1 = *reinterpret_cast<const bf16x8*>(
          &ks[(size_t)(32 + l31) * 64 + (((dc * 2 + hi) ^ sw) * 8)]);
      s0 = __builtin_amdgcn_mfma_f32_32x32x16_bf16(k0, qf[dc], s0, 0, 0, 0);
      s1 = __builtin_amdgcn_mfma_f32_32x32x16_bf16(k1, qf[dc], s1, 0, 0, 0);
    }
    __builtin_amdgcn_s_setprio(0);

    union { uint32_t u[4]; bf16x8 v; } pc;
    // half 0
    {
      float p[16];
#pragma unroll
      for (int r = 0; r < 16; ++r) {
        const int sh = (r & 3) + 8 * (r >> 2);
        uint32_t msel = (uint32_t)__builtin_amdgcn_sbfe((int)w0, sh, 1);
        p[r] = fast_exp2(mask_sel(msel, s0[r], -1e9f));
        l_run += p[r];
      }
      uint32_t a0 = pk_bf16(p[0], p[1]),  a1 = pk_bf16(p[2], p[3]);
      uint32_t b0 = pk_bf16(p[4], p[5]),  b1 = pk_bf16(p[6], p[7]);
      uint32_t c0 = pk_bf16(p[8], p[9]),  c1 = pk_bf16(p[10], p[11]);
      uint32_t d0 = pk_bf16(p[12], p[13]), d1 = pk_bf16(p[14], p[15]);
      half_swap(a0, b0); half_swap(a1, b1);
      half_swap(c0, d0); half_swap(c1, d1);
      __builtin_amdgcn_s_setprio(1);
      pc.u[0] = a0; pc.u[1] = a1; pc.u[2] = b0; pc.u[3] = b1;
      {
        bf16x8 v0 = *reinterpret_cast<const bf16x8*>(
            &vs[(size_t)(l31) * 64 + (((0 + hi) ^ sw) * 8)]);
        bf16x8 v1 = *reinterpret_cast<const bf16x8*>(
            &vs[(size_t)(32 + l31) * 64 + (((0 + hi) ^ sw) * 8)]);
        acc0 = __builtin_amdgcn_mfma_f32_32x32x16_bf16(pc.v, v0, acc0, 0, 0, 0);
        acc1 = __builtin_amdgcn_mfma_f32_32x32x16_bf16(pc.v, v1, acc1, 0, 0, 0);
      }
      pc.u[0] = c0; pc.u[1] = c1; pc.u[2] = d0; pc.u[3] = d1;
      {
        bf16x8 v0 = *reinterpret_cast<const bf16x8*>(
            &vs[(size_t)(l31) * 64 + (((2 + hi) ^ sw) * 8)]);
        bf16x8 v1 = *reinterpret_cast<const bf16x8*>(
            &vs[(size_t)(32 + l31) * 64 + (((2 + hi) ^ sw) * 8)]);
        acc0 = __builtin_amdgcn_mfma_f32_32x32x16_bf16(pc.v, v0, acc0, 0, 0, 0);
        acc1 = __builtin_amdgcn_mfma_f32_32x32x16_bf16(pc.v, v1, acc1, 0, 0, 0);
      }
      __builtin_amdgcn_s_setprio(0);
    }
    // half 1
    {
      float p[16];
#pragma unroll
      for (int r = 0; r < 16; ++r) {
        const int sh = (r & 3) + 8 * (r >> 2);
        uint32_t msel = (uint32_t)__builtin_amdgcn_sbfe((int)w1, sh, 1);
        p[r] = fast_exp2(mask_sel(msel, s1[r], -1e9f));
        l_run += p[r];
      }
      uint32_t a0 = pk_bf16(p[0], p[1]),  a1 = pk_bf16(p[2], p[3]);
      uint32_t b0 = pk_bf16(p[4], p[5]),  b1 = pk_bf16(p[6], p[7]);
      uint32_t c0 = pk_bf16(p[8], p[9]),  c1 = pk_bf16(p[10], p[11]);
      uint32_t d0 = pk_bf16(p[12], p[13]), d1 = pk_bf16(p[14], p[15]);
      half_swap(a0, b0); half_swap(a1, b1);
      half_swap(c0, d0); half_swap(c1, d1);
      __builtin_amdgcn_s_setprio(1);
      pc.u[0] = a0; pc.u[1] = a1; pc.u[2] = b0; pc.u[3] = b1;
      {
        bf16x8 v0 = *reinterpret_cast<const bf16x8*>(
            &vs[(size_t)(l31) * 64 + (((4 + hi) ^ sw) * 8)]);
        bf16x8 v1 = *reinterpret_cast<const bf16x8*>(
            &vs[(size_t)(32 + l31) * 64 + (((4 + hi) ^ sw) * 8)]);
        acc0 = __builtin_amdgcn_mfma_f32_32x32x16_bf16(pc.v, v0, acc0, 0, 0, 0);
        acc1 = __builtin_amdgcn_mfma_f32_32x32x16_bf16(pc.v, v1, acc1, 0, 0, 0);
      }
      pc.u[0] = c0; pc.u[1] = c1; pc.u[2] = d0; pc.u[3] = d1;
      {
        bf16x8 v0 = *reinterpret_cast<const bf16x8*>(
            &vs[(size_t)(l31) * 64 + (((6 + hi) ^ sw) * 8)]);
        bf16x8 v1 = *reinterpret_cast<const bf16x8*>(
            &vs[(size_t)(32 + l31) * 64 + (((6 + hi) ^ sw) * 8)]);
        acc0 = __builtin_amdgcn_mfma_f32_32x32x16_bf16(pc.v, v0, acc0, 0, 0, 0);
        acc1 = __builtin_amdgcn_mfma_f32_32x32x16_bf16(pc.v, v1, acc1, 0, 0, 0);
      }
      __builtin_amdgcn_s_setprio(0);
    }

    mw = mw_next;
    asm volatile("s_waitcnt vmcnt(0)" ::: "memory");
    __syncthreads();
  }

  // ---- cross-group combine (exact: plain sums, shared zero offset) ----
  l_run += __shfl_xor(l_run, 32);

  if (grp == 1) {
    float* myacc = &accC[(wq * 64 + lane) * 32];
#pragma unroll
    for (int r = 0; r < 16; ++r) { myacc[r] = acc0[r]; myacc[16 + r] = acc1[r]; }
    if (hi == 0) lC[wq * 32 + l31] = l_run;
  }
  __syncthreads();

  if (grp == 0) {
    const float* oacc = &accC[(wq * 64 + lane) * 32];
#pragma unroll
    for (int r = 0; r < 16; ++r) { acc0[r] += oacc[r]; acc1[r] += oacc[16 + r]; }
    float l_tot = l_run + lC[wq * 32 + l31];
    if (hi == 0) sRedW[l31] = l_tot;
    asm volatile("s_waitcnt lgkmcnt(0)" ::: "memory");
#pragma unroll
    for (int r = 0; r < 16; ++r) {
      int cr = (r & 3) + 8 * (r >> 2) + 4 * hi;
      float linv = 1.0f / sRedW[cr];
      int qrow = q0g + cr;
      size_t base = ((size_t)b * SEQ + qrow) * DMODEL + h * 64 + l31;
      AO[base]      = __float2bfloat16(acc0[r] * linv);
      AO[base + 32] = __float2bfloat16(acc1[r] * linv);
    }
  }
}

// ---------------- launch ----------------

extern "C" void kernel_launch(void* const* d_in, const int* in_sizes, int n_in,
                              void* d_out, int out_size, void* d_ws, size_t ws_size,
                              hipStream_t stream) {
  const float* q    = (const float*)d_in[0];
  const float* k    = (const float*)d_in[1];
  const float* v    = (const float*)d_in[2];
  const int*   mask = (const int*)d_in[3];
  const float* wQ_w = (const float*)d_in[4];
  const float* wQ_b = (const float*)d_in[5];
  const float* wK_w = (const float*)d_in[6];
  const float* wK_b = (const float*)d_in[7];
  const float* wV_w = (const float*)d_in[8];
  const float* wV_b = (const float*)d_in[9];
  const float* wO_w = (const float*)d_in[10];
  const float* wO_b = (const float*)d_in[11];

  char* ws = (char*)d_ws;
  const size_t SZ_X = (size_t)MROWS * DMODEL * 2;   // 8 MiB
  const size_t SZ_W = (size_t)DMODEL * DMODEL * 2;  // 2 MiB
  __hip_bfloat16* Xq  = (__hip_bfloat16*)(ws);
  __hip_bfloat16* Xk  = (__hip_bfloat16*)(ws + SZ_X);
  __hip_bfloat16* Xv  = (__hip_bfloat16*)(ws + 2 * SZ_X);
  __hip_bfloat16* Wq  = (__hip_bfloat16*)(ws + 3 * SZ_X);
  __hip_bfloat16* Wk  = (__hip_bfloat16*)(ws + 3 * SZ_X + SZ_W);
  __hip_bfloat16* Wv  = (__hip_bfloat16*)(ws + 3 * SZ_X + 2 * SZ_W);
  __hip_bfloat16* Wo  = (__hip_bfloat16*)(ws + 3 * SZ_X + 3 * SZ_W);
  __hip_bfloat16* Qh  = (__hip_bfloat16*)(ws + 3 * SZ_X + 4 * SZ_W);
  __hip_bfloat16* Kh  = (__hip_bfloat16*)(ws + 4 * SZ_X + 4 * SZ_W);
  __hip_bfloat16* VhT = (__hip_bfloat16*)(ws + 5 * SZ_X + 4 * SZ_W);
  __hip_bfloat16* AO  = (__hip_bfloat16*)(ws + 6 * SZ_X + 4 * SZ_W);
  uint32_t*       MB  = (uint32_t*)      (ws + 7 * SZ_X + 4 * SZ_W);

  cast_kernel<<<16384, 256, 0, stream>>>(q, k, v, wQ_w, wK_w, wV_w, wO_w,
                                         (ushort4*)ws);
  mask_kernel<<<8192, 256, 0, stream>>>(mask, MB);

  qkv_gemm_kernel<<<dim3(MROWS / 128, DMODEL / 128, 3), 256, 0, stream>>>(
      Xq, Xk, Xv, Wq, Wk, Wv, wQ_b, wK_b, wV_b, Qh, Kh, VhT);

  attn_kernel<<<dim3(SEQ / 128, NHEADS), 512, 0, stream>>>(
      Qh, Kh, VhT, MB, AO, 0);
  attn_kernel<<<dim3(SEQ / 128, NHEADS), 512, 0, stream>>>(
      Qh, Kh, VhT, MB, AO, NHEADS);

  out_gemm_kernel<<<dim3(MROWS / 64, DMODEL / 128), 256, 0, stream>>>(
      AO, Wo, wO_b, (float*)d_out);
}